// Round 5
// baseline (778.598 us; speedup 1.0000x reference)
//
#include <hip/hip_runtime.h>
#include <math.h>

#define LEAKY(x) ((x) >= 0.f ? (x) : 0.3f*(x))

// ---- workspace float offsets ----
#define G_OFF   0         // 648     extracted g~ (72x9)
#define IM_OFF  648       // 7776    im (b,ch,81)
#define LAM_OFF 8424      // 32      lambda per batch
#define WB_OFF  8456      // 2592    w branch (b,81)
#define YBR_OFF 11048     // 82944   y branch (b,81,32)
#define X1_OFF  93992     // 663552  conv51 out (b,36,36,16)
#define X2_OFF  757544    // 331776  conv15 out (b,18,18,32)
#define X3_OFF  1089320   // 165888  conv55 out (b,9,9,64)

#define OUT0 106272       // elements in output 0; cs_out follows

// ======================= prep =======================
__global__ __launch_bounds__(256) void prep_kernel(
    const float* __restrict__ inp, const float* __restrict__ mat,
    const float* __restrict__ w1_k, const float* __restrict__ w1_b,
    const float* __restrict__ x1_k, const float* __restrict__ x1_b,
    const float* __restrict__ y17_k, const float* __restrict__ y17_b,
    const float* __restrict__ y71_k, const float* __restrict__ y71_b,
    const float* __restrict__ yc_k, const float* __restrict__ yc_b,
    const float* __restrict__ d1_k, const float* __restrict__ d2_k,
    const float* __restrict__ h1_w, const float* __restrict__ h1_b,
    const float* __restrict__ h2_w, const float* __restrict__ h2_b,
    const float* __restrict__ h3_w, const float* __restrict__ h3_b,
    float* __restrict__ ws)
{
    int t = threadIdx.x;
    if (blockIdx.x == 0) {
        // extract separable factor: g[i][a] = mat[i*72, a*9] / sqrt(mat[0,0])
        float rs = rsqrtf(mat[0]);
        for (int u = t; u < 648; u += 256) {
            int i = u / 9, a = u % 9;
            ws[G_OFF + u] = mat[(size_t)(i*72)*81 + a*9] * rs;
        }
        return;
    }
    int b = blockIdx.x - 1;
    __shared__ float sin_[243];
    __shared__ float cm[27];
    __shared__ float cat[5184];
    __shared__ float z1[108];
    __shared__ float z2[24];
    __shared__ float v1[24];
    __shared__ float v2[12];

    const float BN  = 1.0f / sqrtf(1.001f);
    const float BN2 = BN * BN;

    for (int u = t; u < 243; u += 256) sin_[u] = inp[b*243 + u];
    __syncthreads();

    // w branch (t<81), colmax (81..107), d1 conv (128..235)
    if (t < 81) {
        float s = w1_b[0];
        for (int i = 0; i < 3; ++i) s += sin_[t*3+i] * w1_k[i];
        ws[WB_OFF + b*81 + t] = LEAKY(s);
    } else if (t < 108) {
        int u = t - 81;                       // c*3+ch
        float m = 0.f;
        for (int r = 0; r < 9; ++r) m = fmaxf(m, fabsf(sin_[r*27 + u]));
        cm[u] = 0.001f + m;
    }
    if (t >= 128 && t < 236) {
        int u = t - 128;                      // oy*36 + ox*12 + o
        int o = u % 12, ox = (u/12) % 3, oy = u/36;
        float s = 0.f;
        for (int kh = 0; kh < 5; ++kh) {
            int iy = oy*3 - 1 + kh;
            if (iy < 0 || iy > 8) continue;
            for (int kw = 0; kw < 5; ++kw) {
                int ix = ox*3 - 1 + kw;
                if (ix < 0 || ix > 8) continue;
                for (int i = 0; i < 3; ++i)
                    s += sin_[(iy*9+ix)*3 + i] * d1_k[((kh*5+kw)*3 + i)*12 + o];
            }
        }
        z1[u] = LEAKY(BN2 * s);
    }
    __syncthreads();

    // im = leaky(conv1x1(inp / colmax)) ; layout (b,ch,81)
    if (t < 243) {
        int o = t / 81, p = t % 81;
        int c = p % 9;
        float s = x1_b[o];
        for (int i = 0; i < 3; ++i)
            s += (sin_[p*3+i] / cm[c*3+i]) * x1_k[i*3 + o];
        ws[IM_OFF + (b*3 + o)*81 + p] = LEAKY(s);
    }
    __syncthreads();

    // d2 conv: 3x3x12 -> 1x1x24 (kernel rows/cols 1..3 valid)
    if (t < 24) {
        float s = 0.f;
        for (int kh = 1; kh < 4; ++kh)
            for (int kw = 1; kw < 4; ++kw)
                for (int i = 0; i < 12; ++i)
                    s += z1[((kh-1)*3 + (kw-1))*12 + i] * d2_k[((kh*5+kw)*12 + i)*24 + t];
        z2[t] = LEAKY(BN * s);
    }
    __syncthreads();
    if (t < 24) {
        float s = h1_b[t];
        for (int i = 0; i < 24; ++i) s += z2[i] * h1_w[i*24 + t];
        v1[t] = s;
    }
    __syncthreads();
    if (t < 12) {
        float s = h2_b[t];
        for (int i = 0; i < 24; ++i) s += v1[i] * h2_w[i*12 + t];
        v2[t] = s;
    }
    __syncthreads();
    if (t == 0) {
        float s = h3_b[0];
        for (int i = 0; i < 12; ++i) s += v2[i] * h3_w[i];
        ws[LAM_OFF + b] = 0.01f / (1.f + expf(-s));   // 0.1*sigmoid * 0.1
    }

    // y branch: cat = [y1(32) | y2(32)] per position
    for (int u = t; u < 5184; u += 256) {
        int pos = u / 64, i = u % 64;
        int r = pos / 9, c = pos % 9;
        float s;
        if (i < 32) {
            s = y17_b[i];
            for (int kw = 0; kw < 7; ++kw) {
                int cc = c - 3 + kw;
                if (cc < 0 || cc > 8) continue;
                for (int ii = 0; ii < 3; ++ii)
                    s += sin_[(r*9+cc)*3 + ii] * y17_k[(kw*3+ii)*32 + i];
            }
        } else {
            int i2 = i - 32;
            s = y71_b[i2];
            for (int kh = 0; kh < 7; ++kh) {
                int rr = r - 3 + kh;
                if (rr < 0 || rr > 8) continue;
                for (int ii = 0; ii < 3; ++ii)
                    s += sin_[(rr*9+c)*3 + ii] * y71_k[(kh*3+ii)*32 + i2];
            }
        }
        cat[pos*64 + i] = s;
    }
    __syncthreads();
    for (int u = t; u < 2592; u += 256) {
        int pos = u / 32, o = u % 32;
        float s = yc_b[o];
        for (int i = 0; i < 64; ++i) s += cat[pos*64 + i] * yc_k[i*32 + o];
        ws[YBR_OFF + (b*81 + pos)*32 + o] = LEAKY(s);
    }
}

// ======================= FISTA =======================
// 576 threads = 9 waves. t = j*8 + g: lane owns rows g*9..g*9+8 of column j.
// All intra-wave reductions on the VALU DPP pipe (zero LDS, zero barriers).
// LDS only for the cross-wave funnel (S partial sets down, R back up).
// 2 barriers/iter.
//
// ALL per-thread state is NAMED SCALARS (macro-expanded), no arrays:
// the AMDGPU PromoteAlloca pass refuses to promote large per-thread arrays
// (Gr[81] in R3/R4) to registers regardless of __launch_bounds__, sending
// them to scratch: VGPR=84, WRITE_SIZE 20.5MB of scratch writebacks,
// VALUBusy 8.6%, 549us. Named scalars have no alloca -> must be registers.
// __launch_bounds__(576,3) caps VGPR at 170; live set ~140 fits.

#define DPP_XOR1 0xB1   // quad_perm {1,0,3,2}
#define DPP_XOR2 0x4E   // quad_perm {2,3,0,1}
#define DPP_HM   0x141  // row_half_mirror (cross-quad within 8; quads uniform)
#define DPP_ROR8 0x128  // row_ror:8 == lane xor 8 within 16-lane row

template<int CTRL>
__device__ __forceinline__ float dppadd(float v) {
    return v + __int_as_float(__builtin_amdgcn_update_dpp(
        0, __float_as_int(v), CTRL, 0xF, 0xF, true));
}

// G row s (9 named scalars per row)
#define GDECL(s) float G##s##_0,G##s##_1,G##s##_2,G##s##_3,G##s##_4, \
                       G##s##_5,G##s##_6,G##s##_7,G##s##_8;
#define GLOAD(s) { const float* gp = g + gg*81 + s*9; \
    G##s##_0=gp[0]; G##s##_1=gp[1]; G##s##_2=gp[2]; G##s##_3=gp[3]; \
    G##s##_4=gp[4]; G##s##_5=gp[5]; G##s##_6=gp[6]; G##s##_7=gp[7]; \
    G##s##_8=gp[8]; }

// qt butterfly over g-groups (b-split: lane gg holds term b=gg; b=8 on gg==7)
#define QTB(a) { float v = q##a*Gjg + s8_##a*w8; \
    v = dppadd<DPP_XOR1>(v); v = dppadd<DPP_XOR2>(v); v = dppadd<DPP_HM>(v); \
    q##a = v; }

// y-update for owned row s + u partial accumulation
#define STEP(s) { \
    float re = G##s##_0*q0 + G##s##_1*q1 + G##s##_2*q2 + G##s##_3*q3 \
             + G##s##_4*q4 + G##s##_5*q5 + G##s##_6*q6 + G##s##_7*q7 \
             + G##s##_8*q8; \
    float wv = Yv##s + re; \
    float cl = fminf(fmaxf(wv, -lam), lam); \
    float yn = wv - cl; \
    float yx = yn + cmom*(yn - Yl##s); \
    Yl##s = yn; Yv##s = yx; \
    u0 += yx*G##s##_0; u1 += yx*G##s##_1; u2 += yx*G##s##_2; \
    u3 += yx*G##s##_3; u4 += yx*G##s##_4; u5 += yx*G##s##_5; \
    u6 += yx*G##s##_6; u7 += yx*G##s##_7; u8 += yx*G##s##_8; }

// T butterfly over g-groups, then S partials folded over j-pairs (ror8)
#define TSP(a) { float v = u##a; \
    v = dppadd<DPP_XOR1>(v); v = dppadd<DPP_XOR2>(v); v = dppadd<DPP_HM>(v); \
    float vA = v*Gjg, vB = v*Gj8; \
    spA_##a = dppadd<DPP_ROR8>(vA); spB_##a = dppadd<DPP_ROR8>(vB); }

#define OUTW(s) cs_out[(size_t)(b*5184 + (gg*9+s)*72 + j)*3 + ch] = Yl##s;

__global__ __launch_bounds__(576, 3) void fista_kernel(
    const float* __restrict__ ws, float* __restrict__ cs_out)
{
    __shared__ __align__(16) float SPm[36*108];  // 36 sets x (9 slots x 12 pad)
    __shared__ __align__(16) float Rm[108];      // R[b][a], rows of 12

    int t = threadIdx.x;
    int b = blockIdx.x / 3, ch = blockIdx.x % 3;
    const float* g = ws + G_OFF;
    float lam = ws[LAM_OFF + b];

    int j = t >> 3, gg = t & 7;      // column j, row-group g
    int l = t & 63;                  // lane in wave

    // ---- per-thread G constants as 81 named scalar registers ----
    GDECL(0) GDECL(1) GDECL(2) GDECL(3) GDECL(4) GDECL(5) GDECL(6) GDECL(7) GDECL(8)
    GLOAD(0) GLOAD(1) GLOAD(2) GLOAD(3) GLOAD(4) GLOAD(5) GLOAD(6) GLOAD(7) GLOAD(8)

    float Gjg = g[j*9 + gg];         // g[j][gg]
    float Gj8 = g[j*9 + 8];          // g[j][8]
    float w8  = (gg == 7) ? Gj8 : 0.f;   // b=8 qt-term counted on one lane only

    // reducer role (t < 324): ab = a*9+b pair, pp = 4-way set split
    int ab = t >> 2, pp = t & 3;
    int aa = ab / 9, bb = ab % 9;
    float im_ab = (t < 324) ? ws[IM_OFF + (b*3 + ch)*81 + ab] : 0.f;

    // init R = im (transposed: Rm[b][a] = im[a][b])
    if (t < 81) {
        Rm[(t % 9)*12 + (t / 9)] = ws[IM_OFF + (b*3 + ch)*81 + t];
    }

    float Yv0=0,Yv1=0,Yv2=0,Yv3=0,Yv4=0,Yv5=0,Yv6=0,Yv7=0,Yv8=0;
    float Yl0=0,Yl1=0,Yl2=0,Yl3=0,Yl4=0,Yl5=0,Yl6=0,Yl7=0,Yl8=0;
    float tk = 1.f;
    __syncthreads();

    for (int it = 0; it < 100; ++it) {
        float tn = 0.5f*(1.f + sqrtf(1.f + 4.f*tk*tk));
        float cmom = (tk - 1.f) / tn;
        tk = tn;

        // ---- qt[a] = sum_b R[b][a]*g[j][b], b-split + g-butterfly
        const float4* Rg4 = (const float4*)(&Rm[gg*12]);
        float4 ra = Rg4[0], rb = Rg4[1];
        float  rc = Rm[gg*12 + 8];
        float q0=ra.x,q1=ra.y,q2=ra.z,q3=ra.w,
              q4=rb.x,q5=rb.y,q6=rb.z,q7=rb.w,q8=rc;
        const float4* R84 = (const float4*)(&Rm[96]);
        float4 sa = R84[0], sb = R84[1];
        float  sc = Rm[104];
        float s8_0=sa.x,s8_1=sa.y,s8_2=sa.z,s8_3=sa.w,
              s8_4=sb.x,s8_5=sb.y,s8_6=sb.z,s8_7=sb.w,s8_8=sc;
        QTB(0) QTB(1) QTB(2) QTB(3) QTB(4) QTB(5) QTB(6) QTB(7) QTB(8)

        // ---- y-update for 9 owned rows + u partials
        float u0=0,u1=0,u2=0,u3=0,u4=0,u5=0,u6=0,u7=0,u8=0;
        STEP(0) STEP(1) STEP(2) STEP(3) STEP(4) STEP(5) STEP(6) STEP(7) STEP(8)
        if (it == 99) break;

        // ---- T butterfly + S partials (j-pair folded)
        float spA_0,spA_1,spA_2,spA_3,spA_4,spA_5,spA_6,spA_7,spA_8;
        float spB_0,spB_1,spB_2,spB_3,spB_4,spB_5,spB_6,spB_7,spB_8;
        TSP(0) TSP(1) TSP(2) TSP(3) TSP(4) TSP(5) TSP(6) TSP(7) TSP(8)

        // ---- store partial sets: set = wave*4 + row; slot gg (and slot 8)
        int setb = ((t >> 6)*4 + (l >> 4))*108;
        if ((l & 8) == 0) {
            float* d = &SPm[setb + gg*12];
            ((float4*)d)[0] = make_float4(spA_0,spA_1,spA_2,spA_3);
            ((float4*)d)[1] = make_float4(spA_4,spA_5,spA_6,spA_7);
            d[8] = spA_8;
            if (gg == 0) {
                float* d2 = &SPm[setb + 96];
                ((float4*)d2)[0] = make_float4(spB_0,spB_1,spB_2,spB_3);
                ((float4*)d2)[1] = make_float4(spB_4,spB_5,spB_6,spB_7);
                d2[8] = spB_8;
            }
        }
        __syncthreads();

        // ---- reduce 36 sets -> S -> R = im - S
        if (t < 324) {
            float s = 0.f;
#pragma unroll
            for (int k = 0; k < 9; ++k)
                s += SPm[(pp*9 + k)*108 + bb*12 + aa];
            s = dppadd<DPP_XOR1>(s);
            s = dppadd<DPP_XOR2>(s);
            if (pp == 0) Rm[bb*12 + aa] = im_ab - s;
        }
        __syncthreads();
    }

    // ---- output: rows gg*9+s of column j
    OUTW(0) OUTW(1) OUTW(2) OUTW(3) OUTW(4) OUTW(5) OUTW(6) OUTW(7) OUTW(8)
}

// ======================= post convs =======================
__global__ __launch_bounds__(256) void c51_kernel(
    const float* __restrict__ cs, const float* __restrict__ k,
    const float* __restrict__ bias, float* __restrict__ out)
{
    int id = blockIdx.x*256 + threadIdx.x;
    if (id >= 32*36*36*16) return;
    int o = id & 15; int rest = id >> 4;
    int ox = rest % 36; rest /= 36; int oy = rest % 36; int b = rest / 36;
    float s = bias[o];
    int ix = ox*2;
    for (int kh = 0; kh < 5; ++kh) {
        int iy = oy*2 - 1 + kh;
        if (iy < 0 || iy >= 72) continue;
        const float* p = cs + ((size_t)(b*72 + iy)*72 + ix)*3;
        const float* kk = k + kh*48 + o;
        s += p[0]*kk[0] + p[1]*kk[16] + p[2]*kk[32];
    }
    out[id] = s;
}

__global__ __launch_bounds__(256) void c15_kernel(
    const float* __restrict__ x1, const float* __restrict__ k,
    const float* __restrict__ bias, float* __restrict__ out)
{
    int id = blockIdx.x*256 + threadIdx.x;
    if (id >= 32*18*18*32) return;
    int o = id & 31; int rest = id >> 5;
    int ox = rest % 18; rest /= 18; int oy = rest % 18; int b = rest / 18;
    float s = bias[o];
    int iy = oy*2;
    for (int kw = 0; kw < 5; ++kw) {
        int ix = ox*2 - 1 + kw;
        if (ix < 0 || ix >= 36) continue;
        const float* p = x1 + ((size_t)(b*36 + iy)*36 + ix)*16;
        const float* kk = k + kw*512 + o;
        for (int i = 0; i < 16; ++i) s += p[i]*kk[i*32];
    }
    out[id] = s;
}

__global__ __launch_bounds__(256) void c55_kernel(
    const float* __restrict__ x2, const float* __restrict__ k,
    const float* __restrict__ bias, float* __restrict__ out)
{
    int id = blockIdx.x*256 + threadIdx.x;
    if (id >= 32*9*9*64) return;
    int o = id & 63; int rest = id >> 6;
    int ox = rest % 9; rest /= 9; int oy = rest % 9; int b = rest / 9;
    float s = bias[o];
    for (int kh = 0; kh < 5; ++kh) {
        int iy = oy*2 - 1 + kh;
        if (iy < 0 || iy >= 18) continue;
        for (int kw = 0; kw < 5; ++kw) {
            int ix = ox*2 - 1 + kw;
            if (ix < 0 || ix >= 18) continue;
            const float* p = x2 + ((size_t)(b*18 + iy)*18 + ix)*32;
            const float* kk = k + (kh*5+kw)*2048 + o;
            for (int i = 0; i < 32; ++i) s += p[i]*kk[i*64];
        }
    }
    out[id] = s;
}

__global__ __launch_bounds__(256) void out_kernel(
    const float* __restrict__ ws, const float* __restrict__ x2_k,
    const float* __restrict__ x2_b, float* __restrict__ out)
{
    int id = blockIdx.x*256 + threadIdx.x;
    if (id >= OUT0) return;
    int q = id % 41; int rest = id / 41;
    int cc = rest % 9; rest /= 9; int r = rest % 9; int b = rest / 9;
    float val;
    if (q == 0) {
        val = ws[WB_OFF + b*81 + r*9 + cc];
    } else if (q <= 8) {
        int o = q - 1;
        const float* p = ws + X3_OFF + ((size_t)(b*9 + r)*9 + cc)*64;
        float s = x2_b[o];
        for (int i = 0; i < 64; ++i) s += p[i]*x2_k[i*8 + o];
        val = LEAKY(s);
    } else {
        val = ws[YBR_OFF + ((size_t)(b*81 + r*9 + cc))*32 + (q - 9)];
    }
    out[id] = val;
}

// ======================= launch =======================
extern "C" void kernel_launch(void* const* d_in, const int* in_sizes, int n_in,
                              void* d_out, int out_size, void* d_ws, size_t ws_size,
                              hipStream_t stream) {
    const float* inp   = (const float*)d_in[0];
    const float* mat   = (const float*)d_in[1];
    const float* w1_k  = (const float*)d_in[2];
    const float* w1_b  = (const float*)d_in[3];
    const float* x1_k  = (const float*)d_in[4];
    const float* x1_b  = (const float*)d_in[5];
    const float* c51_k = (const float*)d_in[6];
    const float* c51_b = (const float*)d_in[7];
    const float* c15_k = (const float*)d_in[8];
    const float* c15_b = (const float*)d_in[9];
    const float* c55_k = (const float*)d_in[10];
    const float* c55_b = (const float*)d_in[11];
    const float* x2_k  = (const float*)d_in[12];
    const float* x2_b  = (const float*)d_in[13];
    const float* y17_k = (const float*)d_in[14];
    const float* y17_b = (const float*)d_in[15];
    const float* y71_k = (const float*)d_in[16];
    const float* y71_b = (const float*)d_in[17];
    const float* yc_k  = (const float*)d_in[18];
    const float* yc_b  = (const float*)d_in[19];
    const float* d1_k  = (const float*)d_in[20];
    const float* d2_k  = (const float*)d_in[21];
    const float* h1_w  = (const float*)d_in[22];
    const float* h1_b  = (const float*)d_in[23];
    const float* h2_w  = (const float*)d_in[24];
    const float* h2_b  = (const float*)d_in[25];
    const float* h3_w  = (const float*)d_in[26];
    const float* h3_b  = (const float*)d_in[27];

    float* ws  = (float*)d_ws;
    float* out = (float*)d_out;
    float* cs  = out + OUT0;

    hipLaunchKernelGGL(prep_kernel, dim3(33), dim3(256), 0, stream,
        inp, mat, w1_k, w1_b, x1_k, x1_b, y17_k, y17_b, y71_k, y71_b,
        yc_k, yc_b, d1_k, d2_k, h1_w, h1_b, h2_w, h2_b, h3_w, h3_b, ws);
    hipLaunchKernelGGL(fista_kernel, dim3(96), dim3(576), 0, stream, ws, cs);
    hipLaunchKernelGGL(c51_kernel, dim3(2592), dim3(256), 0, stream, cs, c51_k, c51_b, ws + X1_OFF);
    hipLaunchKernelGGL(c15_kernel, dim3(1296), dim3(256), 0, stream, ws + X1_OFF, c15_k, c15_b, ws + X2_OFF);
    hipLaunchKernelGGL(c55_kernel, dim3(648), dim3(256), 0, stream, ws + X2_OFF, c55_k, c55_b, ws + X3_OFF);
    hipLaunchKernelGGL(out_kernel, dim3(416), dim3(256), 0, stream, ws, x2_k, x2_b, out);
}

// Round 6
// 375.215 us; speedup vs baseline: 2.0751x; 2.0751x over previous
//
#include <hip/hip_runtime.h>
#include <math.h>

#define LEAKY(x) ((x) >= 0.f ? (x) : 0.3f*(x))

// ---- workspace float offsets ----
#define G_OFF   0         // 648     extracted g~ (72x9)
#define IM_OFF  648       // 7776    im (b,ch,81)
#define LAM_OFF 8424      // 32      lambda per batch
#define WB_OFF  8456      // 2592    w branch (b,81)
#define YBR_OFF 11048     // 82944   y branch (b,81,32)
#define X1_OFF  93992     // 663552  conv51 out (b,36,36,16)
#define X2_OFF  757544    // 331776  conv15 out (b,18,18,32)
#define X3_OFF  1089320   // 165888  conv55 out (b,9,9,64)

#define OUT0 106272       // elements in output 0; cs_out follows

// ======================= prep =======================
__global__ __launch_bounds__(256) void prep_kernel(
    const float* __restrict__ inp, const float* __restrict__ mat,
    const float* __restrict__ w1_k, const float* __restrict__ w1_b,
    const float* __restrict__ x1_k, const float* __restrict__ x1_b,
    const float* __restrict__ y17_k, const float* __restrict__ y17_b,
    const float* __restrict__ y71_k, const float* __restrict__ y71_b,
    const float* __restrict__ yc_k, const float* __restrict__ yc_b,
    const float* __restrict__ d1_k, const float* __restrict__ d2_k,
    const float* __restrict__ h1_w, const float* __restrict__ h1_b,
    const float* __restrict__ h2_w, const float* __restrict__ h2_b,
    const float* __restrict__ h3_w, const float* __restrict__ h3_b,
    float* __restrict__ ws)
{
    int t = threadIdx.x;
    if (blockIdx.x == 0) {
        // extract separable factor: g[i][a] = mat[i*72, a*9] / sqrt(mat[0,0])
        float rs = rsqrtf(mat[0]);
        for (int u = t; u < 648; u += 256) {
            int i = u / 9, a = u % 9;
            ws[G_OFF + u] = mat[(size_t)(i*72)*81 + a*9] * rs;
        }
        return;
    }
    int b = blockIdx.x - 1;
    __shared__ float sin_[243];
    __shared__ float cm[27];
    __shared__ float cat[5184];
    __shared__ float z1[108];
    __shared__ float z2[24];
    __shared__ float v1[24];
    __shared__ float v2[12];

    const float BN  = 1.0f / sqrtf(1.001f);
    const float BN2 = BN * BN;

    for (int u = t; u < 243; u += 256) sin_[u] = inp[b*243 + u];
    __syncthreads();

    // w branch (t<81), colmax (81..107), d1 conv (128..235)
    if (t < 81) {
        float s = w1_b[0];
        for (int i = 0; i < 3; ++i) s += sin_[t*3+i] * w1_k[i];
        ws[WB_OFF + b*81 + t] = LEAKY(s);
    } else if (t < 108) {
        int u = t - 81;                       // c*3+ch
        float m = 0.f;
        for (int r = 0; r < 9; ++r) m = fmaxf(m, fabsf(sin_[r*27 + u]));
        cm[u] = 0.001f + m;
    }
    if (t >= 128 && t < 236) {
        int u = t - 128;                      // oy*36 + ox*12 + o
        int o = u % 12, ox = (u/12) % 3, oy = u/36;
        float s = 0.f;
        for (int kh = 0; kh < 5; ++kh) {
            int iy = oy*3 - 1 + kh;
            if (iy < 0 || iy > 8) continue;
            for (int kw = 0; kw < 5; ++kw) {
                int ix = ox*3 - 1 + kw;
                if (ix < 0 || ix > 8) continue;
                for (int i = 0; i < 3; ++i)
                    s += sin_[(iy*9+ix)*3 + i] * d1_k[((kh*5+kw)*3 + i)*12 + o];
            }
        }
        z1[u] = LEAKY(BN2 * s);
    }
    __syncthreads();

    // im = leaky(conv1x1(inp / colmax)) ; layout (b,ch,81)
    if (t < 243) {
        int o = t / 81, p = t % 81;
        int c = p % 9;
        float s = x1_b[o];
        for (int i = 0; i < 3; ++i)
            s += (sin_[p*3+i] / cm[c*3+i]) * x1_k[i*3 + o];
        ws[IM_OFF + (b*3 + o)*81 + p] = LEAKY(s);
    }
    __syncthreads();

    // d2 conv: 3x3x12 -> 1x1x24 (kernel rows/cols 1..3 valid)
    if (t < 24) {
        float s = 0.f;
        for (int kh = 1; kh < 4; ++kh)
            for (int kw = 1; kw < 4; ++kw)
                for (int i = 0; i < 12; ++i)
                    s += z1[((kh-1)*3 + (kw-1))*12 + i] * d2_k[((kh*5+kw)*12 + i)*24 + t];
        z2[t] = LEAKY(BN * s);
    }
    __syncthreads();
    if (t < 24) {
        float s = h1_b[t];
        for (int i = 0; i < 24; ++i) s += z2[i] * h1_w[i*24 + t];
        v1[t] = s;
    }
    __syncthreads();
    if (t < 12) {
        float s = h2_b[t];
        for (int i = 0; i < 24; ++i) s += v1[i] * h2_w[i*12 + t];
        v2[t] = s;
    }
    __syncthreads();
    if (t == 0) {
        float s = h3_b[0];
        for (int i = 0; i < 12; ++i) s += v2[i] * h3_w[i];
        ws[LAM_OFF + b] = 0.01f / (1.f + expf(-s));   // 0.1*sigmoid * 0.1
    }

    // y branch: cat = [y1(32) | y2(32)] per position
    for (int u = t; u < 5184; u += 256) {
        int pos = u / 64, i = u % 64;
        int r = pos / 9, c = pos % 9;
        float s;
        if (i < 32) {
            s = y17_b[i];
            for (int kw = 0; kw < 7; ++kw) {
                int cc = c - 3 + kw;
                if (cc < 0 || cc > 8) continue;
                for (int ii = 0; ii < 3; ++ii)
                    s += sin_[(r*9+cc)*3 + ii] * y17_k[(kw*3+ii)*32 + i];
            }
        } else {
            int i2 = i - 32;
            s = y71_b[i2];
            for (int kh = 0; kh < 7; ++kh) {
                int rr = r - 3 + kh;
                if (rr < 0 || rr > 8) continue;
                for (int ii = 0; ii < 3; ++ii)
                    s += sin_[(rr*9+c)*3 + ii] * y71_k[(kh*3+ii)*32 + i2];
            }
        }
        cat[pos*64 + i] = s;
    }
    __syncthreads();
    for (int u = t; u < 2592; u += 256) {
        int pos = u / 32, o = u % 32;
        float s = yc_b[o];
        for (int i = 0; i < 64; ++i) s += cat[pos*64 + i] * yc_k[i*32 + o];
        ws[YBR_OFF + (b*81 + pos)*32 + o] = LEAKY(s);
    }
}

// ======================= FISTA =======================
// 576 threads = 9 waves. t = j*8 + gg: lane owns rows i = 8*s + gg (s=0..8)
// of column j (TOEPLITZ row mapping). g~ is Toeplitz: g[i][a] = f(i-8a)
// (fine grid = 8x coarse grid), and f(d) <= 1.2e-12 outside d in [-8,15].
// With i = 8s+gg and a = s+k:  d = gg - 8k  -- independent of s. So each
// thread needs only THREE G registers:
//   gm = f(gg+8) = g[gg+8][0],  g0 = f(gg) = g[gg][0],  gp = f(gg-8) = g[gg][1]
// (k = +-2 terms are <= 1.2e-12: dropped, exact in fp32.)
// re[row s] = gm*qt[s-1] + g0*qt[s] + gp*qt[s+1]  (static indices);
// u[s-1] += yx*gm; u[s] += yx*g0; u[s+1] += yx*gp.
// This kills the 81-per-thread G table that R3-R5 spilled to scratch
// (VGPR cap ~84 for a 9-wave block; allocator refused 140-reg live set:
// FETCH 8MB of scratch, VALUBusy 8%, 549-589us). Live set now ~70 regs.
// Intra-wave reductions stay on the VALU DPP pipe; LDS only for the
// cross-wave funnel; 2 barriers/iter. qt/T/S/R phases identical to R5
// (hardware-verified: R3/R4/R5 all passed).

#define DPP_XOR1 0xB1   // quad_perm {1,0,3,2}
#define DPP_XOR2 0x4E   // quad_perm {2,3,0,1}
#define DPP_HM   0x141  // row_half_mirror (cross-quad within 8; quads uniform)
#define DPP_ROR8 0x128  // row_ror:8 == lane xor 8 within 16-lane row

template<int CTRL>
__device__ __forceinline__ float dppadd(float v) {
    return v + __int_as_float(__builtin_amdgcn_update_dpp(
        0, __float_as_int(v), CTRL, 0xF, 0xF, true));
}

// qt butterfly over g-groups (b-split: lane gg holds term b=gg; b=8 on gg==7)
#define QTB(a) { float v = q##a*Gjg + s8_##a*w8; \
    v = dppadd<DPP_XOR1>(v); v = dppadd<DPP_XOR2>(v); v = dppadd<DPP_HM>(v); \
    q##a = v; }

// y-update for owned row s (i = 8s+gg), 3-term Toeplitz band
#define STEPMID(s,sm,sp) { \
    float re = gm*q##sm + g0*q##s + gp*q##sp; \
    float wv = Yv##s + re; \
    float cl = fminf(fmaxf(wv, -lam), lam); \
    float yn = wv - cl; \
    float yx = yn + cmom*(yn - Yl##s); \
    Yl##s = yn; Yv##s = yx; \
    u##sm += yx*gm; u##s += yx*g0; u##sp += yx*gp; }
#define STEP0 { \
    float re = g0*q0 + gp*q1; \
    float wv = Yv0 + re; \
    float cl = fminf(fmaxf(wv, -lam), lam); \
    float yn = wv - cl; \
    float yx = yn + cmom*(yn - Yl0); \
    Yl0 = yn; Yv0 = yx; \
    u0 += yx*g0; u1 += yx*gp; }
#define STEP8 { \
    float re = gm*q7 + g0*q8; \
    float wv = Yv8 + re; \
    float cl = fminf(fmaxf(wv, -lam), lam); \
    float yn = wv - cl; \
    float yx = yn + cmom*(yn - Yl8); \
    Yl8 = yn; Yv8 = yx; \
    u7 += yx*gm; u8 += yx*g0; }

// T butterfly over g-groups, then S partials folded over j-pairs (ror8)
#define TSP(a) { float v = u##a; \
    v = dppadd<DPP_XOR1>(v); v = dppadd<DPP_XOR2>(v); v = dppadd<DPP_HM>(v); \
    float vA = v*Gjg, vB = v*Gj8; \
    spA_##a = dppadd<DPP_ROR8>(vA); spB_##a = dppadd<DPP_ROR8>(vB); }

#define OUTW(s) cs_out[(size_t)(b*5184 + (8*s+gg)*72 + j)*3 + ch] = Yl##s;

__global__ __launch_bounds__(576, 3) void fista_kernel(
    const float* __restrict__ ws, float* __restrict__ cs_out)
{
    __shared__ __align__(16) float SPm[36*108];  // 36 sets x (9 slots x 12 pad)
    __shared__ __align__(16) float Rm[108];      // R[b][a], rows of 12

    int t = threadIdx.x;
    int b = blockIdx.x / 3, ch = blockIdx.x % 3;
    const float* g = ws + G_OFF;
    float lam = ws[LAM_OFF + b];

    int j = t >> 3, gg = t & 7;      // column j, row-group gg (i = 8s+gg)
    int l = t & 63;                  // lane in wave

    // ---- 3 Toeplitz G registers ----
    float gm = g[(gg + 8)*9 + 0];    // f(gg+8)
    float g0 = g[gg*9 + 0];          // f(gg)
    float gp = g[gg*9 + 1];          // f(gg-8)

    float Gjg = g[j*9 + gg];         // g[j][gg]
    float Gj8 = g[j*9 + 8];          // g[j][8]
    float w8  = (gg == 7) ? Gj8 : 0.f;   // b=8 qt-term counted on one lane only

    // reducer role (t < 324): ab = a*9+b pair, pp = 4-way set split
    int ab = t >> 2, pp = t & 3;
    int aa = ab / 9, bb = ab % 9;
    float im_ab = (t < 324) ? ws[IM_OFF + (b*3 + ch)*81 + ab] : 0.f;

    // init R = im (transposed: Rm[b][a] = im[a][b])
    if (t < 81) {
        Rm[(t % 9)*12 + (t / 9)] = ws[IM_OFF + (b*3 + ch)*81 + t];
    }

    float Yv0=0,Yv1=0,Yv2=0,Yv3=0,Yv4=0,Yv5=0,Yv6=0,Yv7=0,Yv8=0;
    float Yl0=0,Yl1=0,Yl2=0,Yl3=0,Yl4=0,Yl5=0,Yl6=0,Yl7=0,Yl8=0;
    float tk = 1.f;
    __syncthreads();

    for (int it = 0; it < 100; ++it) {
        float tn = 0.5f*(1.f + sqrtf(1.f + 4.f*tk*tk));
        float cmom = (tk - 1.f) / tn;
        tk = tn;

        // ---- qt[a] = sum_b R[b][a]*g[j][b], b-split + g-butterfly
        const float4* Rg4 = (const float4*)(&Rm[gg*12]);
        float4 ra = Rg4[0], rb = Rg4[1];
        float  rc = Rm[gg*12 + 8];
        float q0=ra.x,q1=ra.y,q2=ra.z,q3=ra.w,
              q4=rb.x,q5=rb.y,q6=rb.z,q7=rb.w,q8=rc;
        const float4* R84 = (const float4*)(&Rm[96]);
        float4 sa = R84[0], sb = R84[1];
        float  sc = Rm[104];
        float s8_0=sa.x,s8_1=sa.y,s8_2=sa.z,s8_3=sa.w,
              s8_4=sb.x,s8_5=sb.y,s8_6=sb.z,s8_7=sb.w,s8_8=sc;
        QTB(0) QTB(1) QTB(2) QTB(3) QTB(4) QTB(5) QTB(6) QTB(7) QTB(8)

        // ---- y-update for 9 owned rows + u partials (3-term band)
        float u0=0,u1=0,u2=0,u3=0,u4=0,u5=0,u6=0,u7=0,u8=0;
        STEP0
        STEPMID(1,0,2) STEPMID(2,1,3) STEPMID(3,2,4) STEPMID(4,3,5)
        STEPMID(5,4,6) STEPMID(6,5,7) STEPMID(7,6,8)
        STEP8
        if (it == 99) break;

        // ---- T butterfly + S partials (j-pair folded)
        float spA_0,spA_1,spA_2,spA_3,spA_4,spA_5,spA_6,spA_7,spA_8;
        float spB_0,spB_1,spB_2,spB_3,spB_4,spB_5,spB_6,spB_7,spB_8;
        TSP(0) TSP(1) TSP(2) TSP(3) TSP(4) TSP(5) TSP(6) TSP(7) TSP(8)

        // ---- store partial sets: set = wave*4 + row; slot gg (and slot 8)
        int setb = ((t >> 6)*4 + (l >> 4))*108;
        if ((l & 8) == 0) {
            float* d = &SPm[setb + gg*12];
            ((float4*)d)[0] = make_float4(spA_0,spA_1,spA_2,spA_3);
            ((float4*)d)[1] = make_float4(spA_4,spA_5,spA_6,spA_7);
            d[8] = spA_8;
            if (gg == 0) {
                float* d2 = &SPm[setb + 96];
                ((float4*)d2)[0] = make_float4(spB_0,spB_1,spB_2,spB_3);
                ((float4*)d2)[1] = make_float4(spB_4,spB_5,spB_6,spB_7);
                d2[8] = spB_8;
            }
        }
        __syncthreads();

        // ---- reduce 36 sets -> S -> R = im - S
        if (t < 324) {
            float s = 0.f;
#pragma unroll
            for (int k = 0; k < 9; ++k)
                s += SPm[(pp*9 + k)*108 + bb*12 + aa];
            s = dppadd<DPP_XOR1>(s);
            s = dppadd<DPP_XOR2>(s);
            if (pp == 0) Rm[bb*12 + aa] = im_ab - s;
        }
        __syncthreads();
    }

    // ---- output: rows 8s+gg of column j
    OUTW(0) OUTW(1) OUTW(2) OUTW(3) OUTW(4) OUTW(5) OUTW(6) OUTW(7) OUTW(8)
}

// ======================= post convs =======================
__global__ __launch_bounds__(256) void c51_kernel(
    const float* __restrict__ cs, const float* __restrict__ k,
    const float* __restrict__ bias, float* __restrict__ out)
{
    int id = blockIdx.x*256 + threadIdx.x;
    if (id >= 32*36*36*16) return;
    int o = id & 15; int rest = id >> 4;
    int ox = rest % 36; rest /= 36; int oy = rest % 36; int b = rest / 36;
    float s = bias[o];
    int ix = ox*2;
    for (int kh = 0; kh < 5; ++kh) {
        int iy = oy*2 - 1 + kh;
        if (iy < 0 || iy >= 72) continue;
        const float* p = cs + ((size_t)(b*72 + iy)*72 + ix)*3;
        const float* kk = k + kh*48 + o;
        s += p[0]*kk[0] + p[1]*kk[16] + p[2]*kk[32];
    }
    out[id] = s;
}

__global__ __launch_bounds__(256) void c15_kernel(
    const float* __restrict__ x1, const float* __restrict__ k,
    const float* __restrict__ bias, float* __restrict__ out)
{
    int id = blockIdx.x*256 + threadIdx.x;
    if (id >= 32*18*18*32) return;
    int o = id & 31; int rest = id >> 5;
    int ox = rest % 18; rest /= 18; int oy = rest % 18; int b = rest / 18;
    float s = bias[o];
    int iy = oy*2;
    for (int kw = 0; kw < 5; ++kw) {
        int ix = ox*2 - 1 + kw;
        if (ix < 0 || ix >= 36) continue;
        const float* p = x1 + ((size_t)(b*36 + iy)*36 + ix)*16;
        const float* kk = k + kw*512 + o;
        for (int i = 0; i < 16; ++i) s += p[i]*kk[i*32];
    }
    out[id] = s;
}

__global__ __launch_bounds__(256) void c55_kernel(
    const float* __restrict__ x2, const float* __restrict__ k,
    const float* __restrict__ bias, float* __restrict__ out)
{
    int id = blockIdx.x*256 + threadIdx.x;
    if (id >= 32*9*9*64) return;
    int o = id & 63; int rest = id >> 6;
    int ox = rest % 9; rest /= 9; int oy = rest % 9; int b = rest / 9;
    float s = bias[o];
    for (int kh = 0; kh < 5; ++kh) {
        int iy = oy*2 - 1 + kh;
        if (iy < 0 || iy >= 18) continue;
        for (int kw = 0; kw < 5; ++kw) {
            int ix = ox*2 - 1 + kw;
            if (ix < 0 || ix >= 18) continue;
            const float* p = x2 + ((size_t)(b*18 + iy)*18 + ix)*32;
            const float* kk = k + (kh*5+kw)*2048 + o;
            for (int i = 0; i < 32; ++i) s += p[i]*kk[i*64];
        }
    }
    out[id] = s;
}

__global__ __launch_bounds__(256) void out_kernel(
    const float* __restrict__ ws, const float* __restrict__ x2_k,
    const float* __restrict__ x2_b, float* __restrict__ out)
{
    int id = blockIdx.x*256 + threadIdx.x;
    if (id >= OUT0) return;
    int q = id % 41; int rest = id / 41;
    int cc = rest % 9; rest /= 9; int r = rest % 9; int b = rest / 9;
    float val;
    if (q == 0) {
        val = ws[WB_OFF + b*81 + r*9 + cc];
    } else if (q <= 8) {
        int o = q - 1;
        const float* p = ws + X3_OFF + ((size_t)(b*9 + r)*9 + cc)*64;
        float s = x2_b[o];
        for (int i = 0; i < 64; ++i) s += p[i]*x2_k[i*8 + o];
        val = LEAKY(s);
    } else {
        val = ws[YBR_OFF + ((size_t)(b*81 + r*9 + cc))*32 + (q - 9)];
    }
    out[id] = val;
}

// ======================= launch =======================
extern "C" void kernel_launch(void* const* d_in, const int* in_sizes, int n_in,
                              void* d_out, int out_size, void* d_ws, size_t ws_size,
                              hipStream_t stream) {
    const float* inp   = (const float*)d_in[0];
    const float* mat   = (const float*)d_in[1];
    const float* w1_k  = (const float*)d_in[2];
    const float* w1_b  = (const float*)d_in[3];
    const float* x1_k  = (const float*)d_in[4];
    const float* x1_b  = (const float*)d_in[5];
    const float* c51_k = (const float*)d_in[6];
    const float* c51_b = (const float*)d_in[7];
    const float* c15_k = (const float*)d_in[8];
    const float* c15_b = (const float*)d_in[9];
    const float* c55_k = (const float*)d_in[10];
    const float* c55_b = (const float*)d_in[11];
    const float* x2_k  = (const float*)d_in[12];
    const float* x2_b  = (const float*)d_in[13];
    const float* y17_k = (const float*)d_in[14];
    const float* y17_b = (const float*)d_in[15];
    const float* y71_k = (const float*)d_in[16];
    const float* y71_b = (const float*)d_in[17];
    const float* yc_k  = (const float*)d_in[18];
    const float* yc_b  = (const float*)d_in[19];
    const float* d1_k  = (const float*)d_in[20];
    const float* d2_k  = (const float*)d_in[21];
    const float* h1_w  = (const float*)d_in[22];
    const float* h1_b  = (const float*)d_in[23];
    const float* h2_w  = (const float*)d_in[24];
    const float* h2_b  = (const float*)d_in[25];
    const float* h3_w  = (const float*)d_in[26];
    const float* h3_b  = (const float*)d_in[27];

    float* ws  = (float*)d_ws;
    float* out = (float*)d_out;
    float* cs  = out + OUT0;

    hipLaunchKernelGGL(prep_kernel, dim3(33), dim3(256), 0, stream,
        inp, mat, w1_k, w1_b, x1_k, x1_b, y17_k, y17_b, y71_k, y71_b,
        yc_k, yc_b, d1_k, d2_k, h1_w, h1_b, h2_w, h2_b, h3_w, h3_b, ws);
    hipLaunchKernelGGL(fista_kernel, dim3(96), dim3(576), 0, stream, ws, cs);
    hipLaunchKernelGGL(c51_kernel, dim3(2592), dim3(256), 0, stream, cs, c51_k, c51_b, ws + X1_OFF);
    hipLaunchKernelGGL(c15_kernel, dim3(1296), dim3(256), 0, stream, ws + X1_OFF, c15_k, c15_b, ws + X2_OFF);
    hipLaunchKernelGGL(c55_kernel, dim3(648), dim3(256), 0, stream, ws + X2_OFF, c55_k, c55_b, ws + X3_OFF);
    hipLaunchKernelGGL(out_kernel, dim3(416), dim3(256), 0, stream, ws, x2_k, x2_b, out);
}

// Round 8
// 351.232 us; speedup vs baseline: 2.2168x; 1.0683x over previous
//
#include <hip/hip_runtime.h>
#include <math.h>

#define LEAKY(x) ((x) >= 0.f ? (x) : 0.3f*(x))

// ---- workspace float offsets ----
#define G_OFF   0         // 648     extracted g~ (72x9)
#define IM_OFF  648       // 7776    im (b,ch,81)
#define LAM_OFF 8424      // 32      lambda per batch
#define WB_OFF  8456      // 2592    w branch (b,81)
#define YBR_OFF 11048     // 82944   y branch (b,81,32)
#define X1_OFF  93992     // 663552  conv51 out (b,36,36,16)
#define X2_OFF  757544    // 331776  conv15 out (b,18,18,32)
#define X3_OFF  1089320   // 165888  conv55 out (b,9,9,64)

#define OUT0 106272       // elements in output 0; cs_out follows

// ======================= prep =======================
__global__ __launch_bounds__(256) void prep_kernel(
    const float* __restrict__ inp, const float* __restrict__ mat,
    const float* __restrict__ w1_k, const float* __restrict__ w1_b,
    const float* __restrict__ x1_k, const float* __restrict__ x1_b,
    const float* __restrict__ y17_k, const float* __restrict__ y17_b,
    const float* __restrict__ y71_k, const float* __restrict__ y71_b,
    const float* __restrict__ yc_k, const float* __restrict__ yc_b,
    const float* __restrict__ d1_k, const float* __restrict__ d2_k,
    const float* __restrict__ h1_w, const float* __restrict__ h1_b,
    const float* __restrict__ h2_w, const float* __restrict__ h2_b,
    const float* __restrict__ h3_w, const float* __restrict__ h3_b,
    float* __restrict__ ws)
{
    int t = threadIdx.x;
    if (blockIdx.x == 0) {
        // extract separable factor: g[i][a] = mat[i*72, a*9] / sqrt(mat[0,0])
        float rs = rsqrtf(mat[0]);
        for (int u = t; u < 648; u += 256) {
            int i = u / 9, a = u % 9;
            ws[G_OFF + u] = mat[(size_t)(i*72)*81 + a*9] * rs;
        }
        return;
    }
    int b = blockIdx.x - 1;
    __shared__ float sin_[243];
    __shared__ float cm[27];
    __shared__ float cat[5184];
    __shared__ float z1[108];
    __shared__ float z2[24];
    __shared__ float v1[24];
    __shared__ float v2[12];

    const float BN  = 1.0f / sqrtf(1.001f);
    const float BN2 = BN * BN;

    for (int u = t; u < 243; u += 256) sin_[u] = inp[b*243 + u];
    __syncthreads();

    // w branch (t<81), colmax (81..107), d1 conv (128..235)
    if (t < 81) {
        float s = w1_b[0];
        for (int i = 0; i < 3; ++i) s += sin_[t*3+i] * w1_k[i];
        ws[WB_OFF + b*81 + t] = LEAKY(s);
    } else if (t < 108) {
        int u = t - 81;                       // c*3+ch
        float m = 0.f;
        for (int r = 0; r < 9; ++r) m = fmaxf(m, fabsf(sin_[r*27 + u]));
        cm[u] = 0.001f + m;
    }
    if (t >= 128 && t < 236) {
        int u = t - 128;                      // oy*36 + ox*12 + o
        int o = u % 12, ox = (u/12) % 3, oy = u/36;
        float s = 0.f;
        for (int kh = 0; kh < 5; ++kh) {
            int iy = oy*3 - 1 + kh;
            if (iy < 0 || iy > 8) continue;
            for (int kw = 0; kw < 5; ++kw) {
                int ix = ox*3 - 1 + kw;
                if (ix < 0 || ix > 8) continue;
                for (int i = 0; i < 3; ++i)
                    s += sin_[(iy*9+ix)*3 + i] * d1_k[((kh*5+kw)*3 + i)*12 + o];
            }
        }
        z1[u] = LEAKY(BN2 * s);
    }
    __syncthreads();

    // im = leaky(conv1x1(inp / colmax)) ; layout (b,ch,81)
    if (t < 243) {
        int o = t / 81, p = t % 81;
        int c = p % 9;
        float s = x1_b[o];
        for (int i = 0; i < 3; ++i)
            s += (sin_[p*3+i] / cm[c*3+i]) * x1_k[i*3 + o];
        ws[IM_OFF + (b*3 + o)*81 + p] = LEAKY(s);
    }
    __syncthreads();

    // d2 conv: 3x3x12 -> 1x1x24 (kernel rows/cols 1..3 valid)
    if (t < 24) {
        float s = 0.f;
        for (int kh = 1; kh < 4; ++kh)
            for (int kw = 1; kw < 4; ++kw)
                for (int i = 0; i < 12; ++i)
                    s += z1[((kh-1)*3 + (kw-1))*12 + i] * d2_k[((kh*5+kw)*12 + i)*24 + t];
        z2[t] = LEAKY(BN * s);
    }
    __syncthreads();
    if (t < 24) {
        float s = h1_b[t];
        for (int i = 0; i < 24; ++i) s += z2[i] * h1_w[i*24 + t];
        v1[t] = s;
    }
    __syncthreads();
    if (t < 12) {
        float s = h2_b[t];
        for (int i = 0; i < 24; ++i) s += v1[i] * h2_w[i*12 + t];
        v2[t] = s;
    }
    __syncthreads();
    if (t == 0) {
        float s = h3_b[0];
        for (int i = 0; i < 12; ++i) s += v2[i] * h3_w[i];
        ws[LAM_OFF + b] = 0.01f / (1.f + expf(-s));   // 0.1*sigmoid * 0.1
    }

    // y branch: cat = [y1(32) | y2(32)] per position
    for (int u = t; u < 5184; u += 256) {
        int pos = u / 64, i = u % 64;
        int r = pos / 9, c = pos % 9;
        float s;
        if (i < 32) {
            s = y17_b[i];
            for (int kw = 0; kw < 7; ++kw) {
                int cc = c - 3 + kw;
                if (cc < 0 || cc > 8) continue;
                for (int ii = 0; ii < 3; ++ii)
                    s += sin_[(r*9+cc)*3 + ii] * y17_k[(kw*3+ii)*32 + i];
            }
        } else {
            int i2 = i - 32;
            s = y71_b[i2];
            for (int kh = 0; kh < 7; ++kh) {
                int rr = r - 3 + kh;
                if (rr < 0 || rr > 8) continue;
                for (int ii = 0; ii < 3; ++ii)
                    s += sin_[(rr*9+c)*3 + ii] * y71_k[(kh*3+ii)*32 + i2];
            }
        }
        cat[pos*64 + i] = s;
    }
    __syncthreads();
    for (int u = t; u < 2592; u += 256) {
        int pos = u / 32, o = u % 32;
        float s = yc_b[o];
        for (int i = 0; i < 64; ++i) s += cat[pos*64 + i] * yc_k[i*32 + o];
        ws[YBR_OFF + (b*81 + pos)*32 + o] = LEAKY(s);
    }
}

// ======================= FISTA =======================
// 576 threads = 9 waves. t = j*8 + gg: lane owns rows i = 8*s + gg (s=0..8)
// of column j = 8*w + rr (w = wave = t>>6, rr = j&7). TOEPLITZ everywhere:
// g[i][a] = f(i-8a), f zero outside d in [-8,15].
//
// Row side (R6, proven): re/u use only gm=f(gg+8), g0=f(gg), gp=f(gg-8).
// Column side (this round): g[j][b] = f(8(w-b)+rr) is nonzero ONLY for
// b in {w-1, w, w+1}, with coeffs cm=f(rr+8), c0=f(rr), cp=f(rr-8):
//   - qt[a] = cm*R[w-1][a] + c0*R[w][a] + cp*R[w+1][a]   (3 broadcast LDS
//     rows + 27 fma; replaces the b-split + 27-DPP butterfly and its
//     VALU->DPP hazard stalls on the critical path)
//   - reducer: S[b] gets contributions ONLY from waves {b-1, b, b+1}
//     -> read 3 k-sets instead of 9 (cuts the stride-108 bank conflicts ~3x)
// Skeleton (layout, TSP fold, stores, 2 barriers/iter) unchanged from R6
// (hardware-verified, absmax 0.0078125).

#define DPP_XOR1 0xB1   // quad_perm {1,0,3,2}
#define DPP_XOR2 0x4E   // quad_perm {2,3,0,1}
#define DPP_HM   0x141  // row_half_mirror (cross-quad within 8; quads uniform)
#define DPP_ROR8 0x128  // row_ror:8 == lane xor 8 within 16-lane row

template<int CTRL>
__device__ __forceinline__ float dppadd(float v) {
    return v + __int_as_float(__builtin_amdgcn_update_dpp(
        0, __float_as_int(v), CTRL, 0xF, 0xF, true));
}

// y-update for owned row s (i = 8s+gg), 3-term Toeplitz band
#define STEPMID(s,sm,sp) { \
    float re = gm*q##sm + g0*q##s + gp*q##sp; \
    float wv = Yv##s + re; \
    float cl = fminf(fmaxf(wv, -lam), lam); \
    float yn = wv - cl; \
    float yx = yn + cmom*(yn - Yl##s); \
    Yl##s = yn; Yv##s = yx; \
    u##sm += yx*gm; u##s += yx*g0; u##sp += yx*gp; }
#define STEP0 { \
    float re = g0*q0 + gp*q1; \
    float wv = Yv0 + re; \
    float cl = fminf(fmaxf(wv, -lam), lam); \
    float yn = wv - cl; \
    float yx = yn + cmom*(yn - Yl0); \
    Yl0 = yn; Yv0 = yx; \
    u0 += yx*g0; u1 += yx*gp; }
#define STEP8 { \
    float re = gm*q7 + g0*q8; \
    float wv = Yv8 + re; \
    float cl = fminf(fmaxf(wv, -lam), lam); \
    float yn = wv - cl; \
    float yx = yn + cmom*(yn - Yl8); \
    Yl8 = yn; Yv8 = yx; \
    u7 += yx*gm; u8 += yx*g0; }

// T butterfly over g-groups, then S partials folded over j-pairs (ror8)
#define TSP(a) { float v = u##a; \
    v = dppadd<DPP_XOR1>(v); v = dppadd<DPP_XOR2>(v); v = dppadd<DPP_HM>(v); \
    float vA = v*Gjg, vB = v*Gj8; \
    spA_##a = dppadd<DPP_ROR8>(vA); spB_##a = dppadd<DPP_ROR8>(vB); }

// qt[a] from the 3 banded R rows (values loaded into named scalars)
#define QT3(a) float q##a = cmc*rm_##a + c0c*r0_##a + cpc*rp_##a;

#define OUTW(s) cs_out[(size_t)(b*5184 + (8*s+gg)*72 + j)*3 + ch] = Yl##s;

__global__ __launch_bounds__(576, 3) void fista_kernel(
    const float* __restrict__ ws, float* __restrict__ cs_out)
{
    __shared__ __align__(16) float SPm[36*108];  // 36 sets x (9 slots x 12 pad)
    __shared__ __align__(16) float Rm[108];      // R[b][a], rows of 12

    int t = threadIdx.x;
    int b = blockIdx.x / 3, ch = blockIdx.x % 3;
    const float* g = ws + G_OFF;
    float lam = ws[LAM_OFF + b];

    int j = t >> 3, gg = t & 7;      // column j, row-group gg (i = 8s+gg)
    int l = t & 63;                  // lane in wave
    int w = t >> 6;                  // wave index = j>>3
    int rr = j & 7;                  // j = 8w + rr

    // ---- row-side Toeplitz G registers ----
    float gm = g[(gg + 8)*9 + 0];    // f(gg+8)
    float g0 = g[gg*9 + 0];          // f(gg)
    float gp = g[gg*9 + 1];          // f(gg-8)

    // ---- column-side Toeplitz coeffs (qt and S band) ----
    float cmc = (w > 0) ? g[(rr + 8)*9 + 0] : 0.f;   // f(rr+8), b=w-1
    float c0c = g[rr*9 + 0];                          // f(rr),   b=w
    float cpc = (w < 8) ? g[rr*9 + 1] : 0.f;          // f(rr-8), b=w+1
    int bmr = (w > 0) ? w - 1 : 0;   // clamped row indices (coeff is 0 there)
    int bpr = (w < 8) ? w + 1 : 8;

    float Gjg = g[j*9 + gg];         // g[j][gg]  (TSP store side)
    float Gj8 = g[j*9 + 8];          // g[j][8]

    // reducer role (t < 324): ab = a*9+b pair, pp = row-set split (4 rows)
    int ab = t >> 2, pp = t & 3;
    int aa = ab / 9, bb = ab % 9;
    float im_ab = (t < 324) ? ws[IM_OFF + (b*3 + ch)*81 + ab] : 0.f;

    // init R = im (transposed: Rm[b][a] = im[a][b])
    if (t < 81) {
        Rm[(t % 9)*12 + (t / 9)] = ws[IM_OFF + (b*3 + ch)*81 + t];
    }

    float Yv0=0,Yv1=0,Yv2=0,Yv3=0,Yv4=0,Yv5=0,Yv6=0,Yv7=0,Yv8=0;
    float Yl0=0,Yl1=0,Yl2=0,Yl3=0,Yl4=0,Yl5=0,Yl6=0,Yl7=0,Yl8=0;
    float tk = 1.f;
    __syncthreads();

    for (int it = 0; it < 100; ++it) {
        float tn = 0.5f*(1.f + sqrtf(1.f + 4.f*tk*tk));
        float cmom = (tk - 1.f) / tn;
        tk = tn;

        // ---- qt[a]: 3-term band over broadcast R rows (no DPP, no butterfly)
        float4 mv0 = *(const float4*)(Rm + bmr*12);
        float4 mv1 = *(const float4*)(Rm + bmr*12 + 4);
        float  mv2 = Rm[bmr*12 + 8];
        float rm_0=mv0.x, rm_1=mv0.y, rm_2=mv0.z, rm_3=mv0.w,
              rm_4=mv1.x, rm_5=mv1.y, rm_6=mv1.z, rm_7=mv1.w, rm_8=mv2;
        float4 zv0 = *(const float4*)(Rm + w*12);
        float4 zv1 = *(const float4*)(Rm + w*12 + 4);
        float  zv2 = Rm[w*12 + 8];
        float r0_0=zv0.x, r0_1=zv0.y, r0_2=zv0.z, r0_3=zv0.w,
              r0_4=zv1.x, r0_5=zv1.y, r0_6=zv1.z, r0_7=zv1.w, r0_8=zv2;
        float4 pv0 = *(const float4*)(Rm + bpr*12);
        float4 pv1 = *(const float4*)(Rm + bpr*12 + 4);
        float  pv2 = Rm[bpr*12 + 8];
        float rp_0=pv0.x, rp_1=pv0.y, rp_2=pv0.z, rp_3=pv0.w,
              rp_4=pv1.x, rp_5=pv1.y, rp_6=pv1.z, rp_7=pv1.w, rp_8=pv2;
        QT3(0) QT3(1) QT3(2) QT3(3) QT3(4) QT3(5) QT3(6) QT3(7) QT3(8)

        // ---- y-update for 9 owned rows + u partials (3-term band)
        float u0=0,u1=0,u2=0,u3=0,u4=0,u5=0,u6=0,u7=0,u8=0;
        STEP0
        STEPMID(1,0,2) STEPMID(2,1,3) STEPMID(3,2,4) STEPMID(4,3,5)
        STEPMID(5,4,6) STEPMID(6,5,7) STEPMID(7,6,8)
        STEP8
        if (it == 99) break;

        // ---- T butterfly + S partials (j-pair folded)
        float spA_0,spA_1,spA_2,spA_3,spA_4,spA_5,spA_6,spA_7,spA_8;
        float spB_0,spB_1,spB_2,spB_3,spB_4,spB_5,spB_6,spB_7,spB_8;
        TSP(0) TSP(1) TSP(2) TSP(3) TSP(4) TSP(5) TSP(6) TSP(7) TSP(8)

        // ---- store partial sets: set = wave*4 + row; slot gg (and slot 8)
        int setb = ((t >> 6)*4 + (l >> 4))*108;
        if ((l & 8) == 0) {
            float* d = &SPm[setb + gg*12];
            ((float4*)d)[0] = make_float4(spA_0,spA_1,spA_2,spA_3);
            ((float4*)d)[1] = make_float4(spA_4,spA_5,spA_6,spA_7);
            d[8] = spA_8;
            if (gg == 0) {
                float* d2 = &SPm[setb + 96];
                ((float4*)d2)[0] = make_float4(spB_0,spB_1,spB_2,spB_3);
                ((float4*)d2)[1] = make_float4(spB_4,spB_5,spB_6,spB_7);
                d2[8] = spB_8;
            }
        }
        __syncthreads();

        // ---- reduce: only waves {bb-1, bb, bb+1} contribute to S[.][bb]
        if (t < 324) {
            float s = SPm[(bb*4 + pp)*108 + bb*12 + aa];
            if (bb > 0) s += SPm[((bb-1)*4 + pp)*108 + bb*12 + aa];
            if (bb < 8) s += SPm[((bb+1)*4 + pp)*108 + bb*12 + aa];
            s = dppadd<DPP_XOR1>(s);
            s = dppadd<DPP_XOR2>(s);
            if (pp == 0) Rm[bb*12 + aa] = im_ab - s;
        }
        __syncthreads();
    }

    // ---- output: rows 8s+gg of column j
    OUTW(0) OUTW(1) OUTW(2) OUTW(3) OUTW(4) OUTW(5) OUTW(6) OUTW(7) OUTW(8)
}

// ======================= post convs =======================
__global__ __launch_bounds__(256) void c51_kernel(
    const float* __restrict__ cs, const float* __restrict__ k,
    const float* __restrict__ bias, float* __restrict__ out)
{
    int id = blockIdx.x*256 + threadIdx.x;
    if (id >= 32*36*36*16) return;
    int o = id & 15; int rest = id >> 4;
    int ox = rest % 36; rest /= 36; int oy = rest % 36; int b = rest / 36;
    float s = bias[o];
    int ix = ox*2;
    for (int kh = 0; kh < 5; ++kh) {
        int iy = oy*2 - 1 + kh;
        if (iy < 0 || iy >= 72) continue;
        const float* p = cs + ((size_t)(b*72 + iy)*72 + ix)*3;
        const float* kk = k + kh*48 + o;
        s += p[0]*kk[0] + p[1]*kk[16] + p[2]*kk[32];
    }
    out[id] = s;
}

__global__ __launch_bounds__(256) void c15_kernel(
    const float* __restrict__ x1, const float* __restrict__ k,
    const float* __restrict__ bias, float* __restrict__ out)
{
    int id = blockIdx.x*256 + threadIdx.x;
    if (id >= 32*18*18*32) return;
    int o = id & 31; int rest = id >> 5;
    int ox = rest % 18; rest /= 18; int oy = rest % 18; int b = rest / 18;
    float s = bias[o];
    int iy = oy*2;
    for (int kw = 0; kw < 5; ++kw) {
        int ix = ox*2 - 1 + kw;
        if (ix < 0 || ix >= 36) continue;
        const float* p = x1 + ((size_t)(b*36 + iy)*36 + ix)*16;
        const float* kk = k + kw*512 + o;
        for (int i = 0; i < 16; ++i) s += p[i]*kk[i*32];
    }
    out[id] = s;
}

__global__ __launch_bounds__(256) void c55_kernel(
    const float* __restrict__ x2, const float* __restrict__ k,
    const float* __restrict__ bias, float* __restrict__ out)
{
    int id = blockIdx.x*256 + threadIdx.x;
    if (id >= 32*9*9*64) return;
    int o = id & 63; int rest = id >> 6;
    int ox = rest % 9; rest /= 9; int oy = rest % 9; int b = rest / 9;
    float s = bias[o];
    for (int kh = 0; kh < 5; ++kh) {
        int iy = oy*2 - 1 + kh;
        if (iy < 0 || iy >= 18) continue;
        for (int kw = 0; kw < 5; ++kw) {
            int ix = ox*2 - 1 + kw;
            if (ix < 0 || ix >= 18) continue;
            const float* p = x2 + ((size_t)(b*18 + iy)*18 + ix)*32;
            const float* kk = k + (kh*5+kw)*2048 + o;
            for (int i = 0; i < 32; ++i) s += p[i]*kk[i*64];
        }
    }
    out[id] = s;
}

__global__ __launch_bounds__(256) void out_kernel(
    const float* __restrict__ ws, const float* __restrict__ x2_k,
    const float* __restrict__ x2_b, float* __restrict__ out)
{
    int id = blockIdx.x*256 + threadIdx.x;
    if (id >= OUT0) return;
    int q = id % 41; int rest = id / 41;
    int cc = rest % 9; rest /= 9; int r = rest % 9; int b = rest / 9;
    float val;
    if (q == 0) {
        val = ws[WB_OFF + b*81 + r*9 + cc];
    } else if (q <= 8) {
        int o = q - 1;
        const float* p = ws + X3_OFF + ((size_t)(b*9 + r)*9 + cc)*64;
        float s = x2_b[o];
        for (int i = 0; i < 64; ++i) s += p[i]*x2_k[i*8 + o];
        val = LEAKY(s);
    } else {
        val = ws[YBR_OFF + ((size_t)(b*81 + r*9 + cc))*32 + (q - 9)];
    }
    out[id] = val;
}

// ======================= launch =======================
extern "C" void kernel_launch(void* const* d_in, const int* in_sizes, int n_in,
                              void* d_out, int out_size, void* d_ws, size_t ws_size,
                              hipStream_t stream) {
    const float* inp   = (const float*)d_in[0];
    const float* mat   = (const float*)d_in[1];
    const float* w1_k  = (const float*)d_in[2];
    const float* w1_b  = (const float*)d_in[3];
    const float* x1_k  = (const float*)d_in[4];
    const float* x1_b  = (const float*)d_in[5];
    const float* c51_k = (const float*)d_in[6];
    const float* c51_b = (const float*)d_in[7];
    const float* c15_k = (const float*)d_in[8];
    const float* c15_b = (const float*)d_in[9];
    const float* c55_k = (const float*)d_in[10];
    const float* c55_b = (const float*)d_in[11];
    const float* x2_k  = (const float*)d_in[12];
    const float* x2_b  = (const float*)d_in[13];
    const float* y17_k = (const float*)d_in[14];
    const float* y17_b = (const float*)d_in[15];
    const float* y71_k = (const float*)d_in[16];
    const float* y71_b = (const float*)d_in[17];
    const float* yc_k  = (const float*)d_in[18];
    const float* yc_b  = (const float*)d_in[19];
    const float* d1_k  = (const float*)d_in[20];
    const float* d2_k  = (const float*)d_in[21];
    const float* h1_w  = (const float*)d_in[22];
    const float* h1_b  = (const float*)d_in[23];
    const float* h2_w  = (const float*)d_in[24];
    const float* h2_b  = (const float*)d_in[25];
    const float* h3_w  = (const float*)d_in[26];
    const float* h3_b  = (const float*)d_in[27];

    float* ws  = (float*)d_ws;
    float* out = (float*)d_out;
    float* cs  = out + OUT0;

    hipLaunchKernelGGL(prep_kernel, dim3(33), dim3(256), 0, stream,
        inp, mat, w1_k, w1_b, x1_k, x1_b, y17_k, y17_b, y71_k, y71_b,
        yc_k, yc_b, d1_k, d2_k, h1_w, h1_b, h2_w, h2_b, h3_w, h3_b, ws);
    hipLaunchKernelGGL(fista_kernel, dim3(96), dim3(576), 0, stream, ws, cs);
    hipLaunchKernelGGL(c51_kernel, dim3(2592), dim3(256), 0, stream, cs, c51_k, c51_b, ws + X1_OFF);
    hipLaunchKernelGGL(c15_kernel, dim3(1296), dim3(256), 0, stream, ws + X1_OFF, c15_k, c15_b, ws + X2_OFF);
    hipLaunchKernelGGL(c55_kernel, dim3(648), dim3(256), 0, stream, ws + X2_OFF, c55_k, c55_b, ws + X3_OFF);
    hipLaunchKernelGGL(out_kernel, dim3(416), dim3(256), 0, stream, ws, x2_k, x2_b, out);
}